// Round 2
// baseline (224.568 us; speedup 1.0000x reference)
//
#include <hip/hip_runtime.h>
#include <math.h>

#define NN 8192
#define KDIM 512
#define DD 256
#define CS 32    // prefix chunk size
#define NC 256   // number of chunks

typedef float4 f4;
typedef __attribute__((ext_vector_type(4))) float f4v;  // native vec for nontemporal

// ---------- K1: H = X @ W (f32 vector GEMM, 64x64 tile, BK=32) ----------
__global__ __launch_bounds__(256) void k_gemm(const float* __restrict__ X,
                                              const float* __restrict__ W,
                                              float* __restrict__ H) {
  __shared__ float Xs[32][64];  // [k][r] (transposed)
  __shared__ float Ws[32][64];  // [k][c]
  const int tid = threadIdx.x;
  const int tx = tid & 15;   // col group -> 4 cols
  const int ty = tid >> 4;   // row group -> 4 rows
  const int r0 = blockIdx.x * 64;
  const int c0 = blockIdx.y * 64;
  float acc[4][4] = {};
  for (int k0 = 0; k0 < KDIM; k0 += 32) {
#pragma unroll
    for (int q = 0; q < 2; ++q) {
      int fi = tid + q * 256;       // 0..511 float4 units of X tile (64 rows x 8 f4)
      int r = fi >> 3;
      int kq = fi & 7;
      f4 v = *reinterpret_cast<const f4*>(&X[(size_t)(r0 + r) * KDIM + k0 + kq * 4]);
      Xs[kq * 4 + 0][r] = v.x; Xs[kq * 4 + 1][r] = v.y;
      Xs[kq * 4 + 2][r] = v.z; Xs[kq * 4 + 3][r] = v.w;
    }
#pragma unroll
    for (int q = 0; q < 2; ++q) {
      int fi = tid + q * 256;       // 0..511 float4 units of W tile (32 k x 16 f4)
      int k = fi >> 4;
      int cq = fi & 15;
      f4 v = *reinterpret_cast<const f4*>(&W[(size_t)(k0 + k) * DD + c0 + cq * 4]);
      *reinterpret_cast<f4*>(&Ws[k][cq * 4]) = v;
    }
    __syncthreads();
#pragma unroll
    for (int k = 0; k < 32; ++k) {
      f4 xv = *reinterpret_cast<const f4*>(&Xs[k][ty * 4]);
      f4 wv = *reinterpret_cast<const f4*>(&Ws[k][tx * 4]);
      float xs[4] = {xv.x, xv.y, xv.z, xv.w};
      float ws[4] = {wv.x, wv.y, wv.z, wv.w};
#pragma unroll
      for (int i = 0; i < 4; ++i)
#pragma unroll
        for (int j = 0; j < 4; ++j) acc[i][j] += xs[i] * ws[j];
    }
    __syncthreads();
  }
#pragma unroll
  for (int i = 0; i < 4; ++i) {
    f4 v = {acc[i][0], acc[i][1], acc[i][2], acc[i][3]};
    *reinterpret_cast<f4*>(&H[(size_t)(r0 + ty * 4 + i) * DD + c0 + tx * 4]) = v;
  }
}

// ---------- K2: s = H@a1, t = H@a2, E1 = e^t, E2 = e^{0.2 t} (one wave/row) ----------
__global__ __launch_bounds__(256) void k_rowdots(const float* __restrict__ H,
                                                 const float* __restrict__ a,
                                                 float* __restrict__ s,
                                                 float* __restrict__ t,
                                                 float* __restrict__ E1,
                                                 float* __restrict__ E2) {
  int wid = threadIdx.x >> 6;
  int lane = threadIdx.x & 63;
  int i = blockIdx.x * 4 + wid;
  f4 h  = *reinterpret_cast<const f4*>(&H[(size_t)i * DD + lane * 4]);
  f4 a1 = *reinterpret_cast<const f4*>(&a[lane * 4]);
  f4 a2 = *reinterpret_cast<const f4*>(&a[DD + lane * 4]);
  float p1 = h.x * a1.x + h.y * a1.y + h.z * a1.z + h.w * a1.w;
  float p2 = h.x * a2.x + h.y * a2.y + h.z * a2.z + h.w * a2.w;
  for (int off = 32; off > 0; off >>= 1) {
    p1 += __shfl_down(p1, off);
    p2 += __shfl_down(p2, off);
  }
  if (lane == 0) {
    s[i] = p1;
    t[i] = p2;
    E1[i] = expf(p2);
    E2[i] = expf(0.2f * p2);
  }
}

// ---------- K3: tmax = max(t); c1 = e^{s-m}, c2 = e^{0.2s-m}, m = lrelu(s+tmax) ----------
__global__ __launch_bounds__(1024) void k_tmax_coef(const float* __restrict__ s,
                                                    const float* __restrict__ t,
                                                    float* __restrict__ c1,
                                                    float* __restrict__ c2) {
  __shared__ float red[16];
  int tid = threadIdx.x;
  float m = -1e30f;
  for (int k = tid; k < NN; k += 1024) m = fmaxf(m, t[k]);
  for (int off = 32; off > 0; off >>= 1) m = fmaxf(m, __shfl_down(m, off));
  if ((tid & 63) == 0) red[tid >> 6] = m;
  __syncthreads();
  if (tid < 16) {
    float v = red[tid];
    for (int off = 8; off > 0; off >>= 1) v = fmaxf(v, __shfl_down(v, off));
    if (tid == 0) red[0] = v;
  }
  __syncthreads();
  float tmax = red[0];
  for (int k = tid; k < NN; k += 1024) {
    float si = s[k];
    float e = si + tmax;
    float mm = e > 0.f ? e : 0.2f * e;
    c1[k] = expf(si - mm);
    c2[k] = expf(0.2f * si - mm);
  }
}

// ---------- K4: bitonic sort of t (single block, LDS) ----------
__global__ __launch_bounds__(1024) void k_sort(const float* __restrict__ t,
                                               float* __restrict__ tsort,
                                               int* __restrict__ perm) {
  __shared__ float v[NN];
  __shared__ int ix[NN];
  int tid = threadIdx.x;
  for (int k = tid; k < NN; k += 1024) { v[k] = t[k]; ix[k] = k; }
  for (int size = 2; size <= NN; size <<= 1) {
    for (int stride = size >> 1; stride > 0; stride >>= 1) {
      __syncthreads();
      for (int p = tid; p < NN / 2; p += 1024) {
        int i = ((p & ~(stride - 1)) << 1) | (p & (stride - 1));
        int j = i | stride;
        bool asc = (i & size) == 0;
        float vi = v[i], vj = v[j];
        bool sw = asc ? (vi > vj) : (vi < vj);
        if (sw) {
          v[i] = vj; v[j] = vi;
          int tmp = ix[i]; ix[i] = ix[j]; ix[j] = tmp;
        }
      }
    }
  }
  __syncthreads();
  for (int k = tid; k < NN; k += 1024) { tsort[k] = v[k]; perm[k] = ix[k]; }
}

// ---------- K5a: per-chunk totals of E1*H and E2*H over sorted order ----------
__global__ __launch_bounds__(256) void k_chunk(const float* __restrict__ H,
                                               const float* __restrict__ E1,
                                               const float* __restrict__ E2,
                                               const int* __restrict__ perm,
                                               float* __restrict__ Ctot1,
                                               float* __restrict__ Ctot2,
                                               float* __restrict__ cs1,
                                               float* __restrict__ cs2) {
  int c = blockIdx.x;
  int d = threadIdx.x;
  float s1 = 0.f, s2 = 0.f, a1 = 0.f, a2 = 0.f;
  for (int kk = 0; kk < CS; ++kk) {
    int p = perm[c * CS + kk];
    float e1 = E1[p], e2 = E2[p];
    float h = H[(size_t)p * DD + d];
    s1 += e1 * h; s2 += e2 * h;
    a1 += e1;     a2 += e2;
  }
  Ctot1[c * DD + d] = s1;
  Ctot2[c * DD + d] = s2;
  if (d == 0) { cs1[c] = a1; cs2[c] = a2; }
}

// ---------- K5b: exclusive scan over chunk totals ----------
__global__ __launch_bounds__(256) void k_scan(const float* __restrict__ Ctot1,
                                              const float* __restrict__ Ctot2,
                                              float* __restrict__ Coff1,
                                              float* __restrict__ Coff2,
                                              const float* __restrict__ cs1,
                                              const float* __restrict__ cs2,
                                              float* __restrict__ cso1,
                                              float* __restrict__ cso2) {
  int d = threadIdx.x;
  float r1 = 0.f, r2 = 0.f;
  for (int c = 0; c < NC; ++c) {
    Coff1[c * DD + d] = r1; r1 += Ctot1[c * DD + d];
    Coff2[c * DD + d] = r2; r2 += Ctot2[c * DD + d];
  }
  __shared__ float sv1[NC], sv2[NC];
  float x1 = cs1[d], x2 = cs2[d];
  sv1[d] = x1; sv2[d] = x2;
  __syncthreads();
  for (int off = 1; off < NC; off <<= 1) {
    float y1 = (d >= off) ? sv1[d - off] : 0.f;
    float y2 = (d >= off) ? sv2[d - off] : 0.f;
    __syncthreads();
    sv1[d] += y1; sv2[d] += y2;
    __syncthreads();
  }
  cso1[d] = (d == 0) ? 0.f : sv1[d - 1];
  cso2[d] = (d == 0) ? 0.f : sv2[d - 1];
}

// ---------- K5c: write exclusive prefix arrays PRE1/PRE2 (+ scalar p1s/p2s) ----------
__global__ __launch_bounds__(256) void k_prefix(const float* __restrict__ H,
                                                const float* __restrict__ E1,
                                                const float* __restrict__ E2,
                                                const int* __restrict__ perm,
                                                const float* __restrict__ Coff1,
                                                const float* __restrict__ Coff2,
                                                const float* __restrict__ cso1,
                                                const float* __restrict__ cso2,
                                                float* __restrict__ PRE1,
                                                float* __restrict__ PRE2,
                                                float* __restrict__ p1s,
                                                float* __restrict__ p2s) {
  int c = blockIdx.x;
  int d = threadIdx.x;
  float r1 = Coff1[c * DD + d], r2 = Coff2[c * DD + d];
  float sr1 = 0.f, sr2 = 0.f;
  if (d == 0) { sr1 = cso1[c]; sr2 = cso2[c]; }
  for (int kk = 0; kk < CS; ++kk) {
    int k = c * CS + kk;
    int p = perm[k];
    PRE1[(size_t)k * DD + d] = r1;
    PRE2[(size_t)k * DD + d] = r2;
    float e1 = E1[p], e2 = E2[p];
    float h = H[(size_t)p * DD + d];
    r1 += e1 * h; r2 += e2 * h;
    if (d == 0) { p1s[k] = sr1; p2s[k] = sr2; sr1 += e1; sr2 += e2; }
  }
  if (c == NC - 1) {
    PRE1[(size_t)NN * DD + d] = r1;
    PRE2[(size_t)NN * DD + d] = r2;
    if (d == 0) { p1s[NN] = sr1; p2s[NN] = sr2; }
  }
}

// ---------- K6: per-row finalize: k_i (binary search), Z, f1/f2, out ----------
__global__ __launch_bounds__(256) void k_finalize(const float* __restrict__ s,
                                                  const float* __restrict__ c1,
                                                  const float* __restrict__ c2,
                                                  const float* __restrict__ tsort,
                                                  const float* __restrict__ p1s,
                                                  const float* __restrict__ p2s,
                                                  const float* __restrict__ PRE1,
                                                  const float* __restrict__ PRE2,
                                                  float* __restrict__ out,
                                                  float* __restrict__ f1,
                                                  float* __restrict__ f2) {
  int wid = threadIdx.x >> 6, lane = threadIdx.x & 63;
  int i = blockIdx.x * 4 + wid;
  float key = -s[i];
  int lo = 0, hi = NN;  // count of tsort <= key (wave-uniform: broadcast loads)
  while (lo < hi) {
    int mid = (lo + hi) >> 1;
    if (tsort[mid] <= key) lo = mid + 1; else hi = mid;
  }
  int k = lo;
  float cc1 = c1[i], cc2 = c2[i];
  float Z = cc1 * (p1s[NN] - p1s[k]) + cc2 * p2s[k];
  float rZ = 1.0f / Z;
  if (lane == 0) { f1[i] = rZ * cc1; f2[i] = rZ * cc2; }
  int d = lane * 4;
  f4 P1 = *reinterpret_cast<const f4*>(&PRE1[(size_t)k * DD + d]);
  f4 P2 = *reinterpret_cast<const f4*>(&PRE2[(size_t)k * DD + d]);
  f4 T1 = *reinterpret_cast<const f4*>(&PRE1[(size_t)NN * DD + d]);
  f4 o;
  o.x = rZ * (cc1 * (T1.x - P1.x) + cc2 * P2.x);
  o.y = rZ * (cc1 * (T1.y - P1.y) + cc2 * P2.y);
  o.z = rZ * (cc1 * (T1.z - P1.z) + cc2 * P2.z);
  o.w = rZ * (cc1 * (T1.w - P1.w) + cc2 * P2.w);
  *reinterpret_cast<f4*>(&out[(size_t)i * DD + d]) = o;
}

// ---------- K7: stream A = (s_i + t_j > 0) ? f1_i*E1_j : f2_i*E2_j ----------
__global__ __launch_bounds__(256) void k_astream(const float* __restrict__ s,
                                                 const float* __restrict__ t,
                                                 const float* __restrict__ E1,
                                                 const float* __restrict__ E2,
                                                 const float* __restrict__ f1,
                                                 const float* __restrict__ f2,
                                                 float* __restrict__ A) {
  int j0 = blockIdx.x * 1024 + threadIdx.x * 4;
  int i0 = blockIdx.y * 32;
  f4 t4  = *reinterpret_cast<const f4*>(&t[j0]);
  f4 e14 = *reinterpret_cast<const f4*>(&E1[j0]);
  f4 e24 = *reinterpret_cast<const f4*>(&E2[j0]);
#pragma unroll 4
  for (int rr = 0; rr < 32; ++rr) {
    int i = i0 + rr;
    float ss = s[i], ff1 = f1[i], ff2 = f2[i];
    f4v o;
    float e;
    e = ss + t4.x; o.x = (e > 0.f) ? ff1 * e14.x : ff2 * e24.x;
    e = ss + t4.y; o.y = (e > 0.f) ? ff1 * e14.y : ff2 * e24.y;
    e = ss + t4.z; o.z = (e > 0.f) ? ff1 * e14.z : ff2 * e24.z;
    e = ss + t4.w; o.w = (e > 0.f) ? ff1 * e14.w : ff2 * e24.w;
    __builtin_nontemporal_store(o, reinterpret_cast<f4v*>(&A[(size_t)i * NN + j0]));
  }
}

extern "C" void kernel_launch(void* const* d_in, const int* in_sizes, int n_in,
                              void* d_out, int out_size, void* d_ws, size_t ws_size,
                              hipStream_t stream) {
  const float* X = (const float*)d_in[0];
  const float* W = (const float*)d_in[1];
  const float* a = (const float*)d_in[2];
  float* out = (float*)d_out;                 // [NN*DD]
  float* A = out + (size_t)NN * DD;           // [NN*NN]

  // small vectors in ws (256 KB) — must survive into k_astream
  float* ws = (float*)d_ws;
  float* s  = ws + 0 * NN;
  float* t  = ws + 1 * NN;
  float* E1 = ws + 2 * NN;
  float* E2 = ws + 3 * NN;
  float* c1 = ws + 4 * NN;
  float* c2 = ws + 5 * NN;
  float* f1 = ws + 6 * NN;
  float* f2 = ws + 7 * NN;

  // big scratch inside the A-region of d_out (consumed before k_astream overwrites it)
  float* H     = out;                 // H in out-region; overwritten by k_finalize
  float* PRE1  = A;                   // 8193*256
  float* PRE2  = A + 4194304;         // 8193*256
  float* Ctot1 = A + 8388608;         // NC*DD
  float* Ctot2 = Ctot1 + NC * DD;
  float* Coff1 = Ctot2 + NC * DD;
  float* Coff2 = Coff1 + NC * DD;
  float* cs1   = Coff2 + NC * DD;
  float* cs2   = cs1 + NC;
  float* cso1  = cs2 + NC;
  float* cso2  = cso1 + NC;
  float* p1s   = cso2 + NC;           // NN+1
  float* p2s   = p1s + (NN + 256);    // NN+1
  float* tsort = p2s + (NN + 256);    // NN
  int*   perm  = (int*)(tsort + NN);  // NN

  k_gemm<<<dim3(NN / 64, DD / 64), 256, 0, stream>>>(X, W, H);
  k_rowdots<<<NN / 4, 256, 0, stream>>>(H, a, s, t, E1, E2);
  k_tmax_coef<<<1, 1024, 0, stream>>>(s, t, c1, c2);
  k_sort<<<1, 1024, 0, stream>>>(t, tsort, perm);
  k_chunk<<<NC, 256, 0, stream>>>(H, E1, E2, perm, Ctot1, Ctot2, cs1, cs2);
  k_scan<<<1, 256, 0, stream>>>(Ctot1, Ctot2, Coff1, Coff2, cs1, cs2, cso1, cso2);
  k_prefix<<<NC, 256, 0, stream>>>(H, E1, E2, perm, Coff1, Coff2, cso1, cso2,
                                   PRE1, PRE2, p1s, p2s);
  k_finalize<<<NN / 4, 256, 0, stream>>>(s, c1, c2, tsort, p1s, p2s, PRE1, PRE2,
                                         out, f1, f2);
  k_astream<<<dim3(NN / 1024, NN / 32), 256, 0, stream>>>(s, t, E1, E2, f1, f2, A);
}